// Round 12
// baseline (1441.710 us; speedup 1.0000x reference)
//
#include <hip/hip_runtime.h>
#include <hip/hip_fp16.h>
#include <hip/hip_fp8.h>
#include <math.h>

// ---------------- constants ----------------
#define NN 50000
#define EE 800000
#define ETOT (EE + NN)
#define BB 128
#define DIM 128
#define GHID 32
#define CHUNK 128
#define NCHUNK ((ETOT + CHUNK - 1) / CHUNK)
#define SCB 196

typedef _Float16 f16;
typedef _Float16 f16x2 __attribute__((ext_vector_type(2)));
typedef _Float16 f16x8 __attribute__((ext_vector_type(8)));
typedef float f32x4 __attribute__((ext_vector_type(4)));

struct CurvPack {
  float k[4], sk[4], mx[4];
};

// ---------------- device math helpers ----------------
__device__ __forceinline__ float wsum64(float v) {
#pragma unroll
  for (int m = 32; m; m >>= 1) v += __shfl_xor(v, m, 64);
  return v;
}

__device__ __forceinline__ float tan_k_d(float x, float kv, float sk) {
  if (kv > 0.f) return tanf(x * sk) / sk;
  if (kv < 0.f) return tanhf(x * sk) / sk;
  return x;
}

__device__ __forceinline__ float artan_k_d(float x, float kv, float sk) {
  if (kv > 0.f) return atanf(x * sk) / sk;
  if (kv < 0.f) {
    float t = x * sk;
    t = fminf(fmaxf(t, -1.f + 1e-7f), 1.f - 1e-7f);
    return atanhf(t) / sk;
  }
  return x;
}

__device__ __forceinline__ float proj_scale_d(float n, float kv, float maxn) {
  if (kv < 0.f && n > maxn) return maxn / n;
  return 1.f;
}

// fp8 helpers
__device__ __forceinline__ unsigned char enc8(float x) {
  return (unsigned char)__hip_cvt_float_to_fp8(x, __HIP_SATFINITE, __HIP_E4M3);
}
__device__ __forceinline__ __half2 dec2(unsigned short v) {
  __half2_raw r2 = __hip_cvt_fp8x2_to_halfraw2((__hip_fp8x2_storage_t)v, __HIP_E4M3);
  union { __half2_raw r; __half2 h; } u;
  u.r = r2;
  return u.h;
}

// ---------------- graph preprocessing ----------------
__global__ void k_init(float* __restrict__ deg, int n) {
  int i = blockIdx.x * 256 + threadIdx.x;
  if (i < n) deg[i] = 1.0f;
}

__global__ void k_counts(const int* __restrict__ batch, int* __restrict__ boff,
                         float* __restrict__ counts, int n) {
  int b = threadIdx.x;
  if (b <= 128) {
    int lo = 0, hi = n;
    while (lo < hi) {
      int mid = (lo + hi) >> 1;
      if (batch[mid] < b) lo = mid + 1; else hi = mid;
    }
    boff[b] = lo;
  }
  __syncthreads();
  if (b < 128) counts[b] = (float)(boff[b + 1] - boff[b]);
}

__global__ void k_deg(const int* __restrict__ ei, float* __restrict__ deg, int e) {
  int i = blockIdx.x * 256 + threadIdx.x;
  if (i < e) atomicAdd(&deg[ei[e + i]], 1.0f);
}

__global__ void k_dinv(float* __restrict__ deg, int* __restrict__ ideg, int n) {
  int i = blockIdx.x * 256 + threadIdx.x;
  if (i < n) {
    float d = deg[i];
    ideg[i] = (int)(d + 0.5f);
    deg[i] = 1.0f / sqrtf(d);
  }
}

// ---------------- parallel scan ----------------
__global__ void k_scanA(const int* __restrict__ ideg, int* __restrict__ bsum, int n) {
  __shared__ int ls[4];
  int i = blockIdx.x * 256 + threadIdx.x;
  int v = (i < n) ? ideg[i] : 0;
#pragma unroll
  for (int m = 1; m < 64; m <<= 1) v += __shfl_xor(v, m, 64);
  if ((threadIdx.x & 63) == 0) ls[threadIdx.x >> 6] = v;
  __syncthreads();
  if (threadIdx.x == 0) bsum[blockIdx.x] = ls[0] + ls[1] + ls[2] + ls[3];
}

__global__ void k_scanB(int* __restrict__ bsum, int nb) {
  __shared__ int wsh[4];
  int tid = threadIdx.x;
  int lane = tid & 63, w = tid >> 6;
  int v = (tid < nb) ? bsum[tid] : 0;
  int x = v;
#pragma unroll
  for (int o = 1; o < 64; o <<= 1) {
    int t = __shfl_up(x, o, 64);
    if (lane >= o) x += t;
  }
  if (lane == 63) wsh[w] = x;
  __syncthreads();
  int add = 0;
  for (int k2 = 0; k2 < w; k2++) add += wsh[k2];
  if (tid < nb) bsum[tid] = add + x - v;
}

__global__ void k_scanC(const int* __restrict__ ideg, const int* __restrict__ bsum,
                        int* __restrict__ off, int* __restrict__ cursor, int n) {
  __shared__ int wsh[4];
  int i = blockIdx.x * 256 + threadIdx.x;
  int lane = threadIdx.x & 63, w = threadIdx.x >> 6;
  int v = (i < n) ? ideg[i] : 0;
  int x = v;
#pragma unroll
  for (int o = 1; o < 64; o <<= 1) {
    int t = __shfl_up(x, o, 64);
    if (lane >= o) x += t;
  }
  if (lane == 63) wsh[w] = x;
  __syncthreads();
  int add = bsum[blockIdx.x];
  for (int k2 = 0; k2 < w; k2++) add += wsh[k2];
  int excl = add + x - v;
  if (i < n) {
    off[i] = excl;
    cursor[i] = excl;
  }
  if (i == n - 1) off[n] = excl + v;
}

// ---------------- chunk head nodes + first-occurrence slots ----------------
__global__ void k_bnodes(const int* __restrict__ off, int* __restrict__ bnode, int nchunk,
                         int n) {
  int g = blockIdx.x * 256 + threadIdx.x;
  if (g >= nchunk) return;
  int e0 = g * CHUNK;
  int lo = 0, hi = n;
  while (hi - lo > 1) {
    int mid = (lo + hi) >> 1;
    if (off[mid] <= e0) lo = mid; else hi = mid;
  }
  bnode[g] = lo;
}

__global__ void k_bslot(const int* __restrict__ bnode, int* __restrict__ bslot, int nchunk) {
  int g = blockIdx.x * 256 + threadIdx.x;
  if (g >= nchunk) return;
  int v = bnode[g];
  int lo = 0, hi = g;
  while (lo < hi) {
    int mid = (lo + hi) >> 1;
    if (bnode[mid] < v) lo = mid + 1; else hi = mid;
  }
  bslot[g] = lo;
}

__device__ __forceinline__ bool span_head(const int* bnode, const int* bslot, const int* off,
                                          int g, int& nd) {
  if (bslot[g] != g) return false;
  nd = bnode[g];
  int s = off[nd], e = off[nd + 1];
  return (s / CHUNK) != ((e - 1) / CHUNK);
}

__global__ void k_zeroc(const int* __restrict__ bnode, const int* __restrict__ bslot,
                        const int* __restrict__ off, float* __restrict__ aggc, int nchunk) {
  int g = blockIdx.x * 4 + (threadIdx.x >> 6);
  int lane = threadIdx.x & 63;
  if (g >= nchunk) return;
  int nd;
  if (!span_head(bnode, bslot, off, g, nd)) return;
  float2 z = make_float2(0.f, 0.f);
#pragma unroll
  for (int i = 0; i < 4; i++) ((float2*)aggc)[(size_t)g * 256 + i * 64 + lane] = z;
}

// ---------------- edge placement ----------------
__global__ void k_place(const int* __restrict__ ei, const float* __restrict__ dinv,
                        int* __restrict__ cursor, int2* __restrict__ esw, int e, int n) {
  int i = blockIdx.x * 256 + threadIdx.x;
  int et = e + n;
  if (i >= et) return;
  int r_, c_;
  if (i < e) {
    r_ = ei[i];
    c_ = ei[e + i];
  } else {
    r_ = i - e;
    c_ = i - e;
  }
  int p = atomicAdd(&cursor[c_], 1);
  esw[p] = make_int2(r_, __float_as_int(dinv[r_] * dinv[c_]));
}

// ---------------- per-node prep ----------------
__global__ void k_nodeprep(const float* __restrict__ x, float* __restrict__ scl,
                           float* __restrict__ xnk, int n, CurvPack cp) {
  int wid = blockIdx.x * 4 + (threadIdx.x >> 6);
  int lane = threadIdx.x & 63;
  if (wid >= n) return;
  float2 v = ((const float2*)x)[(size_t)wid * 64 + lane];
  float n2 = wsum64(v.x * v.x + v.y * v.y);
  float nraw = sqrtf(n2);
  if (lane < 4) {
    float kv = cp.k[lane], sk = cp.sk[lane], maxn = cp.mx[lane];
    float nnv = fmaxf(nraw, 1e-15f);
    float tk = tan_k_d(nnv, kv, sk);
    float s = tk / nnv;
    float pn = fmaxf(fabsf(tk) * (nraw / nnv), 1e-15f);
    float ps = proj_scale_d(pn, kv, maxn);
    scl[(size_t)lane * n + wid] = s * ps;
    xnk[(size_t)lane * n + wid] = pn * ps;
  }
}

// ---------------- bias points ----------------
__global__ void k_biaspt_all(const float* __restrict__ eb1, const float* __restrict__ eb2,
                             float* __restrict__ biasb, CurvPack cp) {
  __shared__ float l2[2];
  int blk = blockIdx.x;
  int ex = blk >> 1, layer = blk & 1;
  float kv = cp.k[ex], sk = cp.sk[ex], maxn = cp.mx[ex];
  const float* b = (layer ? eb2 : eb1) + ex * 128;
  float* outb = biasb + blk * 132;
  int j = threadIdx.x;
  float v = b[j];
  float n2 = wsum64(v * v);
  if ((j & 63) == 0) l2[j >> 6] = n2;
  __syncthreads();
  n2 = l2[0] + l2[1];
  float nraw = sqrtf(n2);
  float nnv = fmaxf(nraw, 1e-15f);
  float tk = tan_k_d(nnv, kv, sk);
  float s = tk / nnv;
  float pn = fmaxf(fabsf(tk) * (nraw / nnv), 1e-15f);
  float ps = proj_scale_d(pn, kv, maxn);
  float bp = ps * s * v;
  outb[j] = bp;
  float y2v = wsum64(bp * bp);
  __syncthreads();
  if ((j & 63) == 0) l2[j >> 6] = y2v;
  __syncthreads();
  if (j == 0) outb[128] = l2[0] + l2[1];
}

// ---------------- W -> fp16 hi/lo split ----------------
__global__ void k_w2h(const float* __restrict__ ew1, const float* __restrict__ ew2,
                      f16* __restrict__ whi, f16* __restrict__ wlo) {
  int i = blockIdx.x * 256 + threadIdx.x;
  if (i >= 8 * 16384) return;
  int slot = i >> 14;
  int r = i & 16383;
  int ex = slot >> 1, layer = slot & 1;
  float w = (layer ? ew2 : ew1)[ex * 16384 + r];
  f16 h = (f16)w;
  whi[i] = h;
  wlo[i] = (f16)(w - (float)h);
}

// ---------------- MFMA expert GEMM (fp32 A in-kernel split, fp8 interleaved out) ------
// grid.y = expert. t8 layout: byte = node*512 + (elem>>1)*8 + ex*2 + (elem&1)
__global__ __launch_bounds__(256) void k_matmfma(
    const float* __restrict__ A, int astr, int aoffPerEx, const float* __restrict__ sclB,
    const float* __restrict__ xnkB, const f16* __restrict__ whiB,
    const f16* __restrict__ wloB, const float* __restrict__ biasB, int layer,
    unsigned char* __restrict__ tout, int n, CurvPack cp) {
  __shared__ float red[3][16][4];
  __shared__ float redT[16][4];
  __shared__ float nAs[16], nCs[16], nL[16];
  int ex = blockIdx.y;
  float kv = cp.k[ex], sk = cp.sk[ex], maxn = cp.mx[ex];
  const f16* whi = whiB + (size_t)(ex * 2 + layer) * 16384;
  const f16* wlo = wloB + (size_t)(ex * 2 + layer) * 16384;
  const float* biasb = biasB + (ex * 2 + layer) * 132;
  const float* scale = sclB + (size_t)ex * n;
  const float* xnorm = xnkB + (size_t)ex * n;

  int tid = threadIdx.x;
  int w = tid >> 6;
  int lane = tid & 63;
  int col = lane & 15;
  int quad = lane >> 4;
  int n0w = blockIdx.x * 16;
  if (n0w >= n) return;

  int anodec = min(n0w + col, n - 1);
  const float* arow = A + (size_t)anodec * astr + ex * aoffPerEx;
  int jt0 = w * 2;

  f32x4 acc[2];
  acc[0] = (f32x4){0.f, 0.f, 0.f, 0.f};
  acc[1] = (f32x4){0.f, 0.f, 0.f, 0.f};

#pragma unroll
  for (int kc = 0; kc < 4; kc++) {
    int kb = kc * 32 + quad * 8;
    float4 a0 = *(const float4*)(arow + kb);
    float4 a1 = *(const float4*)(arow + kb + 4);
    float av[8] = {a0.x, a0.y, a0.z, a0.w, a1.x, a1.y, a1.z, a1.w};
    f16x8 Ah, Al;
#pragma unroll
    for (int i = 0; i < 8; i++) {
      f16 h = (f16)av[i];
      Ah[i] = h;
      Al[i] = (f16)(av[i] - (float)h);
    }
#pragma unroll
    for (int j2 = 0; j2 < 2; j2++) {
      const f16* bh = whi + (size_t)((jt0 + j2) * 16 + col) * 128 + kb;
      const f16* bl = wlo + (size_t)((jt0 + j2) * 16 + col) * 128 + kb;
      f16x8 Bh = *(const f16x8*)bh;
      f16x8 Bl = *(const f16x8*)bl;
      acc[j2] = __builtin_amdgcn_mfma_f32_16x16x32_f16(Ah, Bh, acc[j2], 0, 0, 0);
      acc[j2] = __builtin_amdgcn_mfma_f32_16x16x32_f16(Ah, Bl, acc[j2], 0, 0, 0);
      acc[j2] = __builtin_amdgcn_mfma_f32_16x16x32_f16(Al, Bh, acc[j2], 0, 0, 0);
    }
  }

  float bpj[2];
  bpj[0] = biasb[jt0 * 16 + col];
  bpj[1] = biasb[(jt0 + 1) * 16 + col];
  float y2 = biasb[128];

#pragma unroll
  for (int r = 0; r < 4; r++) {
    float s0 = 0.f, s1 = 0.f, s2 = 0.f;
#pragma unroll
    for (int j2 = 0; j2 < 2; j2++) {
      float v = acc[j2][r];
      s0 = fmaf(v, v, s0);
      s1 += fabsf(v);
      s2 = fmaf(v, bpj[j2], s2);
    }
#pragma unroll
    for (int m = 1; m < 16; m <<= 1) {
      s0 += __shfl_xor(s0, m, 64);
      s1 += __shfl_xor(s1, m, 64);
      s2 += __shfl_xor(s2, m, 64);
    }
    if (col == 0) {
      red[0][quad * 4 + r][w] = s0;
      red[1][quad * 4 + r][w] = s1;
      red[2][quad * 4 + r][w] = s2;
    }
  }
  __syncthreads();

  if (tid < 16) {
    int gnode = min(n0w + tid, n - 1);
    float sc = scale[gnode];
    float s0f = (red[0][tid][0] + red[0][tid][1] + red[0][tid][2] + red[0][tid][3]) * sc * sc;
    float s1f = (red[1][tid][0] + red[1][tid][1] + red[1][tid][2] + red[1][tid][3]) * fabsf(sc);
    float s2f = (red[2][tid][0] + red[2][tid][1] + red[2][tid][2] + red[2][tid][3]) * sc;
    float xnr = xnorm[gnode];
    float xn = fmaxf(xnr, 1e-15f);
    float mxraw = sqrtf(s0f);
    float mxv = fmaxf(mxraw, 1e-15f);
    float ar = artan_k_d(xn, kv, sk);
    float c1 = tan_k_d(mxv / xn * ar, kv, sk);
    float s = (s1f == 0.f) ? 0.f : c1 / mxv;
    float pn = fmaxf(fabsf(c1) * (mxraw / mxv), 1e-15f);
    float ps = (s1f == 0.f) ? 1.f : proj_scale_d(pn, kv, maxn);
    s *= ps;
    float x2 = (s * s) * s0f;
    float xy = s * s2f;
    float Aa = 1.f - 2.f * kv * xy - kv * y2;
    float Cc = 1.f + kv * x2;
    float den = fmaxf(1.f - 2.f * kv * xy + (kv * kv) * x2 * y2, 1e-15f);
    nAs[tid] = Aa * s / den * sc;
    nCs[tid] = Cc / den;
  }
  __syncthreads();

#pragma unroll
  for (int r = 0; r < 4; r++) {
    int idx = quad * 4 + r;
    float Asc = nAs[idx], Cs = nCs[idx];
    float t0 = 0.f;
#pragma unroll
    for (int j2 = 0; j2 < 2; j2++) {
      float v = fmaf(Asc, acc[j2][r], Cs * bpj[j2]);
      t0 = fmaf(v, v, t0);
    }
#pragma unroll
    for (int m = 1; m < 16; m <<= 1) t0 += __shfl_xor(t0, m, 64);
    if (col == 0) redT[idx][w] = t0;
  }
  __syncthreads();

  if (tid < 16) {
    float t0f = redT[tid][0] + redT[tid][1] + redT[tid][2] + redT[tid][3];
    float nraw = sqrtf(t0f);
    float ps2 = proj_scale_d(fmaxf(nraw, 1e-15f), kv, maxn);
    float nh = fmaxf(ps2 * nraw, 1e-15f);
    nL[tid] = artan_k_d(nh, kv, sk) / nh * ps2;
  }
  __syncthreads();

#pragma unroll
  for (int r = 0; r < 4; r++) {
    int idx = quad * 4 + r;
    int gnode = n0w + idx;
    if (gnode >= n) continue;
    float Asc = nAs[idx], Cs = nCs[idx], L = nL[idx];
    unsigned char* trow = tout + (size_t)gnode * 512;
#pragma unroll
    for (int j2 = 0; j2 < 2; j2++) {
      float v = fmaf(Asc, acc[j2][r], Cs * bpj[j2]);
      int d = (jt0 + j2) * 16 + col;
      trow[(d >> 1) * 8 + ex * 2 + (d & 1)] = enc8(L * v);
    }
  }
}

// ---------------- fused 4-expert fp8 edge sweep ----------------
// MODE 0: layer-1 -> interior runs write agg1[node][512] fp32 + scl2/xnk2.
// MODE 1: layer-2 -> per-expert logmap0(expmap0) pooling into feats.
template <int MODE>
__global__ __launch_bounds__(256) void k_aggF(
    const int2* __restrict__ esw, const int* __restrict__ off,
    const int* __restrict__ bnode, const int* __restrict__ bslot,
    const int* __restrict__ batch, const unsigned char* __restrict__ t8,
    float* __restrict__ agg1, float* __restrict__ aggc, float* __restrict__ scl2,
    float* __restrict__ xnk2, float* __restrict__ feats, int etot, int n, CurvPack cp) {
  int gw = blockIdx.x * 4 + (threadIdx.x >> 6);
  int lane = threadIdx.x & 63;
  int e0 = gw * CHUNK;
  if (e0 >= etot) return;
  int e1 = min(e0 + CHUNK, etot);
  int bnHead = bnode[gw];
  int slotA = bslot[gw];
  int slotB = ((gw + 1) * CHUNK < etot) ? bslot[gw + 1] : slotA;
  int cur = bnHead;
  int runStart = off[cur];
  int eend = off[cur + 1];
  __half2 hz = __half2half2(__float2half(0.f));
  __half2 axh[4];
#pragma unroll
  for (int e = 0; e < 4; e++) axh[e] = hz;
  float pax[4], pay[4];
#pragma unroll
  for (int e = 0; e < 4; e++) pax[e] = pay[e] = 0.f;
  int bcur = (MODE == 1) ? batch[cur] : 0;

  auto flushInterior = [&]() {
#pragma unroll
    for (int e = 0; e < 4; e++) {
      float2 f = __half22float2(axh[e]);
      if (MODE == 0) {
        ((float2*)agg1)[(size_t)cur * 256 + e * 64 + lane] = f;
        float n2 = wsum64(fmaf(f.x, f.x, f.y * f.y));
        float nraw = sqrtf(n2);
        float nnv = fmaxf(nraw, 1e-15f);
        float tk = tan_k_d(nnv, cp.k[e], cp.sk[e]);
        float s = tk / nnv;
        float pn = fmaxf(fabsf(tk) * (nraw / nnv), 1e-15f);
        float ps = proj_scale_d(pn, cp.k[e], cp.mx[e]);
        if (lane == 0) {
          scl2[(size_t)e * n + cur] = s * ps;
          xnk2[(size_t)e * n + cur] = pn * ps;
        }
      } else {
        float n2 = wsum64(fmaf(f.x, f.x, f.y * f.y));
        float nraw = sqrtf(n2);
        float nnv = fmaxf(nraw, 1e-15f);
        float tk = tan_k_d(nnv, cp.k[e], cp.sk[e]);
        float s = tk / nnv;
        float pn = fmaxf(fabsf(tk) * (nraw / nnv), 1e-15f);
        float ps = proj_scale_d(pn, cp.k[e], cp.mx[e]);
        s *= ps;
        float nh = fmaxf(pn * ps, 1e-15f);
        float sc = artan_k_d(nh, cp.k[e], cp.sk[e]) / nh * s;
        pax[e] = fmaf(sc, f.x, pax[e]);
        pay[e] = fmaf(sc, f.y, pay[e]);
      }
    }
  };
  auto flushBoundary = [&]() {
    int slot = (cur == bnHead) ? slotA : slotB;
#pragma unroll
    for (int e = 0; e < 4; e++) {
      float2 f = __half22float2(axh[e]);
      float* dp = aggc + (size_t)slot * 512 + e * 128 + lane * 2;
      atomicAdd(dp, f.x);
      atomicAdd(dp + 1, f.y);
    }
  };
  auto flushPool = [&]() {
    if (MODE == 1) {
#pragma unroll
      for (int e = 0; e < 4; e++) {
        float* fp = &feats[(size_t)bcur * 512 + e * 128 + lane * 2];
        atomicAdd(fp, pax[e]);
        atomicAdd(fp + 1, pay[e]);
      }
    }
  };

  int j = e0;
  while (j < e1) {
    if (j + 8 <= e1 && eend >= j + 8) {
      int2 m[8];
#pragma unroll
      for (int q = 0; q < 8; q++) m[q] = esw[j + q];
      uint2 rv[8];
#pragma unroll
      for (int q = 0; q < 8; q++) {
        int s = __builtin_amdgcn_readfirstlane(m[q].x);
        rv[q] = *(const uint2*)(t8 + (size_t)s * 512 + lane * 8);
      }
#pragma unroll
      for (int q = 0; q < 8; q++) {
        __half2 wh = __half2half2(__float2half(__int_as_float(m[q].y)));
        axh[0] = __hfma2(wh, dec2((unsigned short)(rv[q].x & 0xffff)), axh[0]);
        axh[1] = __hfma2(wh, dec2((unsigned short)(rv[q].x >> 16)), axh[1]);
        axh[2] = __hfma2(wh, dec2((unsigned short)(rv[q].y & 0xffff)), axh[2]);
        axh[3] = __hfma2(wh, dec2((unsigned short)(rv[q].y >> 16)), axh[3]);
      }
      j += 8;
    } else if (j + 4 <= e1 && eend >= j + 4) {
      int2 m[4];
#pragma unroll
      for (int q = 0; q < 4; q++) m[q] = esw[j + q];
      uint2 rv[4];
#pragma unroll
      for (int q = 0; q < 4; q++) {
        int s = __builtin_amdgcn_readfirstlane(m[q].x);
        rv[q] = *(const uint2*)(t8 + (size_t)s * 512 + lane * 8);
      }
#pragma unroll
      for (int q = 0; q < 4; q++) {
        __half2 wh = __half2half2(__float2half(__int_as_float(m[q].y)));
        axh[0] = __hfma2(wh, dec2((unsigned short)(rv[q].x & 0xffff)), axh[0]);
        axh[1] = __hfma2(wh, dec2((unsigned short)(rv[q].x >> 16)), axh[1]);
        axh[2] = __hfma2(wh, dec2((unsigned short)(rv[q].y & 0xffff)), axh[2]);
        axh[3] = __hfma2(wh, dec2((unsigned short)(rv[q].y >> 16)), axh[3]);
      }
      j += 4;
    } else {
      if (j == eend) {
        if (runStart >= e0) flushInterior(); else flushBoundary();
#pragma unroll
        for (int e = 0; e < 4; e++) axh[e] = hz;
        runStart = j;
        cur++;
        eend = off[cur + 1];
        if (MODE == 1) {
          int nb = batch[cur];
          if (nb != bcur) {
            flushPool();
#pragma unroll
            for (int e = 0; e < 4; e++) pax[e] = pay[e] = 0.f;
            bcur = nb;
          }
        }
      }
      int2 m = esw[j];
      int s = __builtin_amdgcn_readfirstlane(m.x);
      uint2 rv = *(const uint2*)(t8 + (size_t)s * 512 + lane * 8);
      __half2 wh = __half2half2(__float2half(__int_as_float(m.y)));
      axh[0] = __hfma2(wh, dec2((unsigned short)(rv.x & 0xffff)), axh[0]);
      axh[1] = __hfma2(wh, dec2((unsigned short)(rv.x >> 16)), axh[1]);
      axh[2] = __hfma2(wh, dec2((unsigned short)(rv.y & 0xffff)), axh[2]);
      axh[3] = __hfma2(wh, dec2((unsigned short)(rv.y >> 16)), axh[3]);
      j++;
    }
  }
  if (runStart >= e0 && eend <= e1) flushInterior(); else flushBoundary();
  if (MODE == 1) flushPool();
}

// ---------------- gate edge sweep (fp16 rows, 128 halfs/node) ----------------
__global__ __launch_bounds__(256) void k_aggG(
    const int2* __restrict__ esw, const int* __restrict__ off,
    const int* __restrict__ bnode, const int* __restrict__ bslot,
    const int* __restrict__ batch, const f16x2* __restrict__ t, float* __restrict__ aggc,
    const float* __restrict__ bias, float* __restrict__ hgate, int etot, int n) {
  int gw = blockIdx.x * 4 + (threadIdx.x >> 6);
  int lane = threadIdx.x & 63;
  int e0 = gw * CHUNK;
  if (e0 >= etot) return;
  int e1 = min(e0 + CHUNK, etot);
  int bnHead = bnode[gw];
  int slotA = bslot[gw];
  int slotB = ((gw + 1) * CHUNK < etot) ? bslot[gw + 1] : slotA;
  int cur = bnHead;
  int runStart = off[cur];
  int eend = off[cur + 1];
  float ax = 0.f, ay = 0.f, pax = 0.f, pay = 0.f;
  int bcur = batch[cur];
  float2 bb = ((const float2*)bias)[lane];

  auto flushInterior = [&]() {
    pax += fmaxf(ax + bb.x, 0.f);
    pay += fmaxf(ay + bb.y, 0.f);
  };
  auto flushBoundary = [&]() {
    int slot = (cur == bnHead) ? slotA : slotB;
    float* dp = aggc + (size_t)slot * 512 + lane * 2;
    atomicAdd(dp, ax);
    atomicAdd(dp + 1, ay);
  };
  auto flushPool = [&]() {
    float* hp = &hgate[(size_t)bcur * 128 + lane * 2];
    atomicAdd(hp, pax);
    atomicAdd(hp + 1, pay);
  };

  int j = e0;
  while (j < e1) {
    if (j + 8 <= e1 && eend >= j + 8) {
      int2 m[8];
#pragma unroll
      for (int q = 0; q < 8; q++) m[q] = esw[j + q];
      f16x2 r[8];
#pragma unroll
      for (int q = 0; q < 8; q++) {
        int s = __builtin_amdgcn_readfirstlane(m[q].x);
        r[q] = t[(size_t)s * 64 + lane];
      }
#pragma unroll
      for (int q = 0; q < 8; q++) {
        float w = __int_as_float(m[q].y);
        ax = fmaf(w, (float)r[q][0], ax);
        ay = fmaf(w, (float)r[q][1], ay);
      }
      j += 8;
    } else if (j + 4 <= e1 && eend >= j + 4) {
      int2 m[4];
#pragma unroll
      for (int q = 0; q < 4; q++) m[q] = esw[j + q];
      f16x2 r[4];
#pragma unroll
      for (int q = 0; q < 4; q++) {
        int s = __builtin_amdgcn_readfirstlane(m[q].x);
        r[q] = t[(size_t)s * 64 + lane];
      }
#pragma unroll
      for (int q = 0; q < 4; q++) {
        float w = __int_as_float(m[q].y);
        ax = fmaf(w, (float)r[q][0], ax);
        ay = fmaf(w, (float)r[q][1], ay);
      }
      j += 4;
    } else {
      if (j == eend) {
        if (runStart >= e0) flushInterior(); else flushBoundary();
        ax = ay = 0.f;
        runStart = j;
        cur++;
        eend = off[cur + 1];
        int nb = batch[cur];
        if (nb != bcur) {
          flushPool();
          pax = pay = 0.f;
          bcur = nb;
        }
      }
      int2 m = esw[j];
      int s = __builtin_amdgcn_readfirstlane(m.x);
      f16x2 rv = t[(size_t)s * 64 + lane];
      float w = __int_as_float(m.y);
      ax = fmaf(w, (float)rv[0], ax);
      ay = fmaf(w, (float)rv[1], ay);
      j++;
    }
  }
  if (runStart >= e0 && eend <= e1) flushInterior(); else flushBoundary();
  flushPool();
}

// ---------------- fixups for chunk-spanning runs ----------------
__global__ void k_fix1(const int* __restrict__ bnode, const int* __restrict__ bslot,
                       const int* __restrict__ off, const float* __restrict__ aggc,
                       float* __restrict__ agg1, float* __restrict__ scl2,
                       float* __restrict__ xnk2, int nchunk, int n, CurvPack cp) {
  int g = blockIdx.x * 4 + (threadIdx.x >> 6);
  int lane = threadIdx.x & 63;
  if (g >= nchunk) return;
  int nd;
  if (!span_head(bnode, bslot, off, g, nd)) return;
#pragma unroll
  for (int e = 0; e < 4; e++) {
    float2 v = ((const float2*)aggc)[(size_t)g * 256 + e * 64 + lane];
    ((float2*)agg1)[(size_t)nd * 256 + e * 64 + lane] = v;
    float n2 = wsum64(fmaf(v.x, v.x, v.y * v.y));
    float nraw = sqrtf(n2);
    float nnv = fmaxf(nraw, 1e-15f);
    float tk = tan_k_d(nnv, cp.k[e], cp.sk[e]);
    float s = tk / nnv;
    float pn = fmaxf(fabsf(tk) * (nraw / nnv), 1e-15f);
    float ps = proj_scale_d(pn, cp.k[e], cp.mx[e]);
    if (lane == 0) {
      scl2[(size_t)e * n + nd] = s * ps;
      xnk2[(size_t)e * n + nd] = pn * ps;
    }
  }
}

__global__ void k_fix2(const int* __restrict__ bnode, const int* __restrict__ bslot,
                       const int* __restrict__ off, const float* __restrict__ aggc,
                       const int* __restrict__ batch, float* __restrict__ feats, int nchunk,
                       CurvPack cp) {
  int g = blockIdx.x * 4 + (threadIdx.x >> 6);
  int lane = threadIdx.x & 63;
  if (g >= nchunk) return;
  int nd;
  if (!span_head(bnode, bslot, off, g, nd)) return;
  int b = batch[nd];
#pragma unroll
  for (int e = 0; e < 4; e++) {
    float2 v = ((const float2*)aggc)[(size_t)g * 256 + e * 64 + lane];
    float n2 = wsum64(fmaf(v.x, v.x, v.y * v.y));
    float nraw = sqrtf(n2);
    float nnv = fmaxf(nraw, 1e-15f);
    float tk = tan_k_d(nnv, cp.k[e], cp.sk[e]);
    float s = tk / nnv;
    float pn = fmaxf(fabsf(tk) * (nraw / nnv), 1e-15f);
    float ps = proj_scale_d(pn, cp.k[e], cp.mx[e]);
    s *= ps;
    float nh = fmaxf(pn * ps, 1e-15f);
    float sc = artan_k_d(nh, cp.k[e], cp.sk[e]) / nh * s;
    float* fp = &feats[(size_t)b * 512 + e * 128 + lane * 2];
    atomicAdd(fp, sc * v.x);
    atomicAdd(fp + 1, sc * v.y);
  }
}

__global__ void k_fixG(const int* __restrict__ bnode, const int* __restrict__ bslot,
                       const int* __restrict__ off, const float* __restrict__ aggc,
                       const int* __restrict__ batch, const float* __restrict__ bias,
                       float* __restrict__ hgate, int nchunk) {
  int g = blockIdx.x * 4 + (threadIdx.x >> 6);
  int lane = threadIdx.x & 63;
  if (g >= nchunk) return;
  int nd;
  if (!span_head(bnode, bslot, off, g, nd)) return;
  float2 v = ((const float2*)aggc)[(size_t)g * 256 + lane];
  float2 bb = ((const float2*)bias)[lane];
  int b = batch[nd];
  float* hp = &hgate[(size_t)b * 128 + lane * 2];
  atomicAdd(hp, fmaxf(v.x + bb.x, 0.f));
  atomicAdd(hp + 1, fmaxf(v.y + bb.y, 0.f));
}

// ---------------- gate GEMM 1 ----------------
__global__ __launch_bounds__(256) void k_gate1(const float* __restrict__ x,
                                               const float* __restrict__ gw1,
                                               float* __restrict__ m1, int n) {
  __shared__ float xT[64][68];
  __shared__ float Wt[64][36];
  int tid = threadIdx.x;
  int n0 = blockIdx.x * 64;
  int c = tid & 7, r = tid >> 3;
  float acc[2][4];
#pragma unroll
  for (int i = 0; i < 2; i++)
#pragma unroll
    for (int jj = 0; jj < 4; jj++) acc[i][jj] = 0.f;

  for (int kc = 0; kc < 2; kc++) {
    if (kc) __syncthreads();
#pragma unroll
    for (int it = 0; it < 8; it++) {
      int u = tid + it * 256;
      int j = u >> 6, kd = u & 63;
      Wt[kd][j] = gw1[j * 128 + kc * 64 + kd];
    }
#pragma unroll
    for (int it = 0; it < 4; it++) {
      int u = tid + it * 256;
      int node = u >> 4, c4 = u & 15;
      float4 v = make_float4(0.f, 0.f, 0.f, 0.f);
      if (n0 + node < n) v = ((const float4*)x)[(size_t)(n0 + node) * 32 + kc * 16 + c4];
      xT[4 * c4 + 0][node] = v.x;
      xT[4 * c4 + 1][node] = v.y;
      xT[4 * c4 + 2][node] = v.z;
      xT[4 * c4 + 3][node] = v.w;
    }
    __syncthreads();
#pragma unroll 8
    for (int kd = 0; kd < 64; kd++) {
      float2 av = *(const float2*)&xT[kd][r * 2];
      float4 bv = *(const float4*)&Wt[kd][c * 4];
      float a[2] = {av.x, av.y};
      float bbv[4] = {bv.x, bv.y, bv.z, bv.w};
#pragma unroll
      for (int i = 0; i < 2; i++)
#pragma unroll
        for (int jj = 0; jj < 4; jj++) acc[i][jj] = fmaf(a[i], bbv[jj], acc[i][jj]);
    }
  }
#pragma unroll
  for (int i = 0; i < 2; i++) {
    int node = n0 + r * 2 + i;
    if (node >= n) continue;
    ((float4*)m1)[(size_t)node * 8 + c] = make_float4(acc[i][0], acc[i][1], acc[i][2], acc[i][3]);
  }
}

// ---------------- gate GEMM 2 (fp16 out, row 128 halfs) ----------------
__global__ __launch_bounds__(256) void k_gate2(const float* __restrict__ g1,
                                               const float* __restrict__ gw2,
                                               f16* __restrict__ m2, int n) {
  __shared__ float xT[32][68];
  __shared__ float Wt[32][132];
  int tid = threadIdx.x;
  int n0 = blockIdx.x * 64;
  int c = tid & 15, r = tid >> 4;
  float acc[4][8];
#pragma unroll
  for (int i = 0; i < 4; i++)
#pragma unroll
    for (int jj = 0; jj < 8; jj++) acc[i][jj] = 0.f;

#pragma unroll
  for (int it = 0; it < 16; it++) {
    int u = tid + it * 256;
    int j = u >> 5, kd = u & 31;
    Wt[kd][j] = gw2[j * 32 + kd];
  }
#pragma unroll
  for (int it = 0; it < 2; it++) {
    int u = tid + it * 256;
    int node = u >> 3, c4 = u & 7;
    float4 v = make_float4(0.f, 0.f, 0.f, 0.f);
    if (n0 + node < n) v = ((const float4*)g1)[(size_t)(n0 + node) * 8 + c4];
    xT[4 * c4 + 0][node] = v.x;
    xT[4 * c4 + 1][node] = v.y;
    xT[4 * c4 + 2][node] = v.z;
    xT[4 * c4 + 3][node] = v.w;
  }
  __syncthreads();
#pragma unroll 8
  for (int kd = 0; kd < 32; kd++) {
    float4 av = *(const float4*)&xT[kd][r * 4];
    float4 b0 = *(const float4*)&Wt[kd][c * 8];
    float4 b1 = *(const float4*)&Wt[kd][c * 8 + 4];
    float a[4] = {av.x, av.y, av.z, av.w};
    float bbv[8] = {b0.x, b0.y, b0.z, b0.w, b1.x, b1.y, b1.z, b1.w};
#pragma unroll
    for (int i = 0; i < 4; i++)
#pragma unroll
      for (int jj = 0; jj < 8; jj++) acc[i][jj] = fmaf(a[i], bbv[jj], acc[i][jj]);
  }
#pragma unroll
  for (int i = 0; i < 4; i++) {
    int node = n0 + r * 4 + i;
    if (node >= n) continue;
    f16x8 hv;
#pragma unroll
    for (int jj = 0; jj < 8; jj++) hv[jj] = (f16)acc[i][jj];
    *((f16x8*)(m2 + (size_t)node * 128) + c) = hv;
  }
}

// ---------------- gate aggregation dim32 ----------------
__global__ void k_agg_relu32(const float* __restrict__ m1, const int* __restrict__ off,
                             const int2* __restrict__ esw, const float* __restrict__ bias,
                             float* __restrict__ g1, int n) {
  int node = blockIdx.x * 4 + (threadIdx.x >> 6);
  int lane = threadIdx.x & 63;
  if (node >= n) return;
  int grp = lane >> 3, l8 = lane & 7;
  int e0 = off[node], e1 = off[node + 1];
  float4 acc = make_float4(0.f, 0.f, 0.f, 0.f);
  for (int base = e0 + grp; base < e1; base += 8) {
    int2 me = esw[base];
    int ss = me.x;
    float ww = __int_as_float(me.y);
    float4 tv = ((const float4*)m1)[(size_t)ss * 8 + l8];
    acc.x = fmaf(ww, tv.x, acc.x);
    acc.y = fmaf(ww, tv.y, acc.y);
    acc.z = fmaf(ww, tv.z, acc.z);
    acc.w = fmaf(ww, tv.w, acc.w);
  }
#pragma unroll
  for (int m = 8; m <= 32; m <<= 1) {
    acc.x += __shfl_xor(acc.x, m, 64);
    acc.y += __shfl_xor(acc.y, m, 64);
    acc.z += __shfl_xor(acc.z, m, 64);
    acc.w += __shfl_xor(acc.w, m, 64);
  }
  if (grp == 0) {
    float4 bb = ((const float4*)bias)[l8];
    float4 o = make_float4(fmaxf(acc.x + bb.x, 0.f), fmaxf(acc.y + bb.y, 0.f),
                           fmaxf(acc.z + bb.z, 0.f), fmaxf(acc.w + bb.w, 0.f));
    ((float4*)g1)[(size_t)node * 8 + l8] = o;
  }
}

// ---------------- final ----------------
__global__ __launch_bounds__(128) void k_final(const float* __restrict__ feats,
                                               const float* __restrict__ hgate,
                                               const float* __restrict__ counts,
                                               const float* __restrict__ gate_u,
                                               const float* __restrict__ tau_raw,
                                               float* __restrict__ out, CurvPack cp) {
  __shared__ float l2[2];
  int b = blockIdx.x;
  int j = threadIdx.x;
  float cnt = fmaxf(counts[b], 1.f);
  float hg = hgate[(size_t)b * 128 + j] / cnt;

  auto bsum = [&](float v) -> float {
    v = wsum64(v);
    __syncthreads();
    if ((j & 63) == 0) l2[j >> 6] = v;
    __syncthreads();
    return l2[0] + l2[1];
  };

  float nhg2 = bsum(hg * hg);
  float nhgraw = sqrtf(nhg2);
  float nhg = fmaxf(nhgraw, 1e-15f);

  float d[4], tau[4];
#pragma unroll
  for (int i = 0; i < 4; i++) {
    float kv = cp.k[i], sk = cp.sk[i], mxn = cp.mx[i];
    float tk = tan_k_d(nhg, kv, sk);
    float s = tk / nhg;
    float pn = fmaxf(fabsf(tk) * (nhgraw / nhg), 1e-15f);
    s *= proj_scale_d(pn, kv, mxn);
    float zk = s * hg;

    float u = gate_u[i * 128 + j];
    float nu2 = bsum(u * u);
    float nuraw = sqrtf(nu2);
    float nu = fmaxf(nuraw, 1e-15f);
    float tku = tan_k_d(nu, kv, sk);
    float su = tku / nu;
    float pnu = fmaxf(fabsf(tku) * (nuraw / nu), 1e-15f);
    su *= proj_scale_d(pnu, kv, mxn);
    float yk = su * u;

    float xv = -zk;
    float x2 = bsum(xv * xv);
    float y2 = bsum(yk * yk);
    float xy = bsum(xv * yk);
    float A = 1.f - 2.f * kv * xy - kv * y2;
    float C = 1.f + kv * x2;
    float den = fmaxf(1.f - 2.f * kv * xy + (kv * kv) * x2 * y2, 1e-15f);
    float ma = (A * xv + C * yk) / den;
    float m2 = bsum(ma * ma);
    float mraw = sqrtf(m2);
    float ps2 = proj_scale_d(fmaxf(mraw, 1e-15f), kv, mxn);
    float nm = fmaxf(ps2 * mraw, 1e-15f);
    d[i] = 2.f * artan_k_d(nm, kv, sk);

    float tr = tau_raw[i];
    tau[i] = fminf(fmaxf(log1pf(expf(tr)) + 0.05f, 0.05f), 10.f);
  }

  float xi[4];
  float mxv = -1e30f;
#pragma unroll
  for (int i = 0; i < 4; i++) {
    xi[i] = -d[i] / tau[i];
    mxv = fmaxf(mxv, xi[i]);
  }
  float es = 0.f, e[4];
#pragma unroll
  for (int i = 0; i < 4; i++) {
    e[i] = expf(xi[i] - mxv);
    es += e[i];
  }
  float w[4];
#pragma unroll
  for (int i = 0; i < 4; i++) w[i] = e[i] / es;

#pragma unroll
  for (int i = 0; i < 4; i++)
    out[(size_t)b * 512 + i * 128 + j] = feats[(size_t)b * 512 + i * 128 + j] / cnt * w[i];

  if (j < 4) {
    out[65536 + b * 4 + j] = w[j];
    out[66048 + b * 4 + j] = d[j];
  }
  if (b == 0 && j < 4) out[66560 + j] = tau[j];
}

// ---------------- host launcher ----------------
extern "C" void kernel_launch(void* const* d_in, const int* in_sizes, int n_in,
                              void* d_out, int out_size, void* d_ws, size_t ws_size,
                              hipStream_t stream) {
  const float* x = (const float*)d_in[0];
  const int* ei = (const int*)d_in[1];
  const int* batch = (const int*)d_in[2];
  const float* ew1 = (const float*)d_in[3];
  const float* eb1 = (const float*)d_in[4];
  const float* ew2 = (const float*)d_in[5];
  const float* eb2 = (const float*)d_in[6];
  const float* gw1 = (const float*)d_in[7];
  const float* gb1 = (const float*)d_in[8];
  const float* gw2 = (const float*)d_in[9];
  const float* gb2 = (const float*)d_in[10];
  const float* gu = (const float*)d_in[11];
  const float* traw = (const float*)d_in[12];
  float* out = (float*)d_out;

  const int N = NN, E = EE, ET = ETOT, B = BB;

  float* ws = (float*)d_ws;
  size_t o = 0;
  unsigned char* t8 = (unsigned char*)ws;  o += (size_t)N * 128;  // N*512 bytes fp8
  float* agg1 = ws + o;     o += (size_t)N * 512;
  float* aggc = ws + o;     o += (size_t)NCHUNK * 512;
  float* deg = ws + o;      o += N;
  float* scl1 = ws + o;     o += (size_t)4 * N;
  float* xnk1 = ws + o;     o += (size_t)4 * N;
  float* scl2 = ws + o;     o += (size_t)4 * N;
  float* xnk2 = ws + o;     o += (size_t)4 * N;
  float* counts = ws + o;   o += 256;
  float* feats = ws + o;    o += (size_t)B * 512;
  float* hg = ws + o;       o += (size_t)B * 128;
  float* biasb = ws + o;    o += 8 * 132;
  f16* whi = (f16*)(ws + o);    o += 8 * 16384 / 2;
  f16* wlo = (f16*)(ws + o);    o += 8 * 16384 / 2;
  int* ideg = (int*)(ws + o);   o += N;
  int* csroff = (int*)(ws + o); o += N + 8;
  int* cursor = (int*)(ws + o); o += N;
  int* boff = (int*)(ws + o);   o += 136;
  int* bsum = (int*)(ws + o);   o += 256;
  int* bnode = (int*)(ws + o);  o += NCHUNK + 8;
  int* bslot = (int*)(ws + o);  o += NCHUNK + 8;
  int2* esw = (int2*)(ws + o);  o += (size_t)2 * ET;

  float* m1 = agg1;                       // gate scratch aliases agg1
  float* g1 = agg1 + (size_t)N * 32;
  f16* tg = (f16*)t8;                     // gate fp16 rows alias t8

  hipMemsetAsync(counts, 0, (256 + (size_t)B * 512 + (size_t)B * 128) * sizeof(float), stream);

  const double curvs[4] = {-1.0, 0.0, 1.0, -0.5};
  CurvPack cp;
  for (int i = 0; i < 4; i++) {
    double kd = curvs[i];
    double skd = sqrt(fabs(kd));
    cp.k[i] = (float)kd;
    cp.sk[i] = (float)skd;
    cp.mx[i] = (kd < 0) ? (float)((1.0 - 1e-5) / skd) : 3.0e38f;
  }

  k_init<<<(N + 255) / 256, 256, 0, stream>>>(deg, N);
  k_counts<<<1, 256, 0, stream>>>(batch, boff, counts, N);
  k_deg<<<(E + 255) / 256, 256, 0, stream>>>(ei, deg, E);
  k_dinv<<<(N + 255) / 256, 256, 0, stream>>>(deg, ideg, N);
  k_scanA<<<SCB, 256, 0, stream>>>(ideg, bsum, N);
  k_scanB<<<1, 256, 0, stream>>>(bsum, SCB);
  k_scanC<<<SCB, 256, 0, stream>>>(ideg, bsum, csroff, cursor, N);
  k_bnodes<<<(NCHUNK + 255) / 256, 256, 0, stream>>>(csroff, bnode, NCHUNK, N);
  k_bslot<<<(NCHUNK + 255) / 256, 256, 0, stream>>>(bnode, bslot, NCHUNK);
  k_place<<<(ET + 255) / 256, 256, 0, stream>>>(ei, deg, cursor, esw, E, N);
  k_nodeprep<<<(N + 3) / 4, 256, 0, stream>>>(x, scl1, xnk1, N, cp);
  k_biaspt_all<<<8, 128, 0, stream>>>(eb1, eb2, biasb, cp);
  k_w2h<<<512, 256, 0, stream>>>(ew1, ew2, whi, wlo);

  const int aggBlocks = (NCHUNK + 3) / 4;
  dim3 mfmaGrid((N + 15) / 16, 4);

  // ---- layer 1 (all 4 experts fused, fp8 t) ----
  k_matmfma<<<mfmaGrid, 256, 0, stream>>>(x, 128, 0, scl1, xnk1, whi, wlo, biasb, 0, t8, N, cp);
  k_zeroc<<<aggBlocks, 256, 0, stream>>>(bnode, bslot, csroff, aggc, NCHUNK);
  k_aggF<0><<<aggBlocks, 256, 0, stream>>>(esw, csroff, bnode, bslot, batch, t8, agg1, aggc,
                                           scl2, xnk2, nullptr, ET, N, cp);
  k_fix1<<<aggBlocks, 256, 0, stream>>>(bnode, bslot, csroff, aggc, agg1, scl2, xnk2, NCHUNK, N,
                                        cp);
  // ---- layer 2 ----
  k_matmfma<<<mfmaGrid, 256, 0, stream>>>(agg1, 512, 128, scl2, xnk2, whi, wlo, biasb, 1, t8, N,
                                          cp);
  k_zeroc<<<aggBlocks, 256, 0, stream>>>(bnode, bslot, csroff, aggc, NCHUNK);
  k_aggF<1><<<aggBlocks, 256, 0, stream>>>(esw, csroff, bnode, bslot, batch, t8, nullptr, aggc,
                                           nullptr, nullptr, feats, ET, N, cp);
  k_fix2<<<aggBlocks, 256, 0, stream>>>(bnode, bslot, csroff, aggc, batch, feats, NCHUNK, cp);

  // ---- gate GCN ----
  k_gate1<<<(N + 63) / 64, 256, 0, stream>>>(x, gw1, m1, N);
  k_agg_relu32<<<(N + 3) / 4, 256, 0, stream>>>(m1, csroff, esw, gb1, g1, N);
  k_gate2<<<(N + 63) / 64, 256, 0, stream>>>(g1, gw2, tg, N);
  k_zeroc<<<aggBlocks, 256, 0, stream>>>(bnode, bslot, csroff, aggc, NCHUNK);
  k_aggG<<<aggBlocks, 256, 0, stream>>>(esw, csroff, bnode, bslot, batch, (const f16x2*)tg,
                                        aggc, gb2, hg, ET, N);
  k_fixG<<<aggBlocks, 256, 0, stream>>>(bnode, bslot, csroff, aggc, batch, gb2, hg, NCHUNK);

  k_final<<<B, 128, 0, stream>>>(feats, hg, counts, gu, traw, out, cp);

  (void)in_sizes; (void)n_in; (void)out_size; (void)ws_size;
}

// Round 13
// 1028.312 us; speedup vs baseline: 1.4020x; 1.4020x over previous
//
#include <hip/hip_runtime.h>
#include <hip/hip_fp16.h>
#include <math.h>

// ---------------- constants ----------------
#define NN 50000
#define EE 800000
#define ETOT (EE + NN)
#define BB 128
#define DIM 128
#define GHID 32
#define CHUNK 128
#define NCHUNK ((ETOT + CHUNK - 1) / CHUNK)
#define SCB 196

typedef _Float16 f16;
typedef _Float16 f16x2 __attribute__((ext_vector_type(2)));
typedef _Float16 f16x8 __attribute__((ext_vector_type(8)));
typedef float f32x4 __attribute__((ext_vector_type(4)));

struct CurvPack {
  float k[4], sk[4], mx[4];
};

// ---------------- device math helpers ----------------
__device__ __forceinline__ float wsum64(float v) {
#pragma unroll
  for (int m = 32; m; m >>= 1) v += __shfl_xor(v, m, 64);
  return v;
}

__device__ __forceinline__ float tan_k_d(float x, float kv, float sk) {
  if (kv > 0.f) return tanf(x * sk) / sk;
  if (kv < 0.f) return tanhf(x * sk) / sk;
  return x;
}

__device__ __forceinline__ float artan_k_d(float x, float kv, float sk) {
  if (kv > 0.f) return atanf(x * sk) / sk;
  if (kv < 0.f) {
    float t = x * sk;
    t = fminf(fmaxf(t, -1.f + 1e-7f), 1.f - 1e-7f);
    return atanhf(t) / sk;
  }
  return x;
}

__device__ __forceinline__ float proj_scale_d(float n, float kv, float maxn) {
  if (kv < 0.f && n > maxn) return maxn / n;
  return 1.f;
}

__device__ __forceinline__ __half2 h2cast(unsigned u) {
  union { unsigned u; __half2 h; } c;
  c.u = u;
  return c.h;
}

// ---------------- graph preprocessing ----------------
__global__ void k_init(float* __restrict__ deg, int n) {
  int i = blockIdx.x * 256 + threadIdx.x;
  if (i < n) deg[i] = 1.0f;
}

__global__ void k_counts(const int* __restrict__ batch, int* __restrict__ boff,
                         float* __restrict__ counts, int n) {
  int b = threadIdx.x;
  if (b <= 128) {
    int lo = 0, hi = n;
    while (lo < hi) {
      int mid = (lo + hi) >> 1;
      if (batch[mid] < b) lo = mid + 1; else hi = mid;
    }
    boff[b] = lo;
  }
  __syncthreads();
  if (b < 128) counts[b] = (float)(boff[b + 1] - boff[b]);
}

__global__ void k_deg(const int* __restrict__ ei, float* __restrict__ deg, int e) {
  int i = blockIdx.x * 256 + threadIdx.x;
  if (i < e) atomicAdd(&deg[ei[e + i]], 1.0f);
}

__global__ void k_dinv(float* __restrict__ deg, int* __restrict__ ideg, int n) {
  int i = blockIdx.x * 256 + threadIdx.x;
  if (i < n) {
    float d = deg[i];
    ideg[i] = (int)(d + 0.5f);
    deg[i] = 1.0f / sqrtf(d);
  }
}

// ---------------- parallel scan ----------------
__global__ void k_scanA(const int* __restrict__ ideg, int* __restrict__ bsum, int n) {
  __shared__ int ls[4];
  int i = blockIdx.x * 256 + threadIdx.x;
  int v = (i < n) ? ideg[i] : 0;
#pragma unroll
  for (int m = 1; m < 64; m <<= 1) v += __shfl_xor(v, m, 64);
  if ((threadIdx.x & 63) == 0) ls[threadIdx.x >> 6] = v;
  __syncthreads();
  if (threadIdx.x == 0) bsum[blockIdx.x] = ls[0] + ls[1] + ls[2] + ls[3];
}

__global__ void k_scanB(int* __restrict__ bsum, int nb) {
  __shared__ int wsh[4];
  int tid = threadIdx.x;
  int lane = tid & 63, w = tid >> 6;
  int v = (tid < nb) ? bsum[tid] : 0;
  int x = v;
#pragma unroll
  for (int o = 1; o < 64; o <<= 1) {
    int t = __shfl_up(x, o, 64);
    if (lane >= o) x += t;
  }
  if (lane == 63) wsh[w] = x;
  __syncthreads();
  int add = 0;
  for (int k2 = 0; k2 < w; k2++) add += wsh[k2];
  if (tid < nb) bsum[tid] = add + x - v;
}

__global__ void k_scanC(const int* __restrict__ ideg, const int* __restrict__ bsum,
                        int* __restrict__ off, int* __restrict__ cursor, int n) {
  __shared__ int wsh[4];
  int i = blockIdx.x * 256 + threadIdx.x;
  int lane = threadIdx.x & 63, w = threadIdx.x >> 6;
  int v = (i < n) ? ideg[i] : 0;
  int x = v;
#pragma unroll
  for (int o = 1; o < 64; o <<= 1) {
    int t = __shfl_up(x, o, 64);
    if (lane >= o) x += t;
  }
  if (lane == 63) wsh[w] = x;
  __syncthreads();
  int add = bsum[blockIdx.x];
  for (int k2 = 0; k2 < w; k2++) add += wsh[k2];
  int excl = add + x - v;
  if (i < n) {
    off[i] = excl;
    cursor[i] = excl;
  }
  if (i == n - 1) off[n] = excl + v;
}

// ---------------- chunk head nodes + first-occurrence slots ----------------
__global__ void k_bnodes(const int* __restrict__ off, int* __restrict__ bnode, int nchunk,
                         int n) {
  int g = blockIdx.x * 256 + threadIdx.x;
  if (g >= nchunk) return;
  int e0 = g * CHUNK;
  int lo = 0, hi = n;
  while (hi - lo > 1) {
    int mid = (lo + hi) >> 1;
    if (off[mid] <= e0) lo = mid; else hi = mid;
  }
  bnode[g] = lo;
}

__global__ void k_bslot(const int* __restrict__ bnode, int* __restrict__ bslot, int nchunk) {
  int g = blockIdx.x * 256 + threadIdx.x;
  if (g >= nchunk) return;
  int v = bnode[g];
  int lo = 0, hi = g;
  while (lo < hi) {
    int mid = (lo + hi) >> 1;
    if (bnode[mid] < v) lo = mid + 1; else hi = mid;
  }
  bslot[g] = lo;
}

__device__ __forceinline__ bool span_head(const int* bnode, const int* bslot, const int* off,
                                          int g, int& nd) {
  if (bslot[g] != g) return false;
  nd = bnode[g];
  int s = off[nd], e = off[nd + 1];
  return (s / CHUNK) != ((e - 1) / CHUNK);
}

__global__ void k_zeroc(const int* __restrict__ bnode, const int* __restrict__ bslot,
                        const int* __restrict__ off, float* __restrict__ aggc, int nchunk) {
  int g = blockIdx.x * 4 + (threadIdx.x >> 6);
  int lane = threadIdx.x & 63;
  if (g >= nchunk) return;
  int nd;
  if (!span_head(bnode, bslot, off, g, nd)) return;
  float2 z = make_float2(0.f, 0.f);
#pragma unroll
  for (int i = 0; i < 4; i++) ((float2*)aggc)[(size_t)g * 256 + i * 64 + lane] = z;
}

// ---------------- edge placement ----------------
__global__ void k_place(const int* __restrict__ ei, const float* __restrict__ dinv,
                        int* __restrict__ cursor, int2* __restrict__ esw, int e, int n) {
  int i = blockIdx.x * 256 + threadIdx.x;
  int et = e + n;
  if (i >= et) return;
  int r_, c_;
  if (i < e) {
    r_ = ei[i];
    c_ = ei[e + i];
  } else {
    r_ = i - e;
    c_ = i - e;
  }
  int p = atomicAdd(&cursor[c_], 1);
  esw[p] = make_int2(r_, __float_as_int(dinv[r_] * dinv[c_]));
}

// ---------------- per-node prep ----------------
__global__ void k_nodeprep(const float* __restrict__ x, float* __restrict__ scl,
                           float* __restrict__ xnk, int n, CurvPack cp) {
  int wid = blockIdx.x * 4 + (threadIdx.x >> 6);
  int lane = threadIdx.x & 63;
  if (wid >= n) return;
  float2 v = ((const float2*)x)[(size_t)wid * 64 + lane];
  float n2 = wsum64(v.x * v.x + v.y * v.y);
  float nraw = sqrtf(n2);
  if (lane < 4) {
    float kv = cp.k[lane], sk = cp.sk[lane], maxn = cp.mx[lane];
    float nnv = fmaxf(nraw, 1e-15f);
    float tk = tan_k_d(nnv, kv, sk);
    float s = tk / nnv;
    float pn = fmaxf(fabsf(tk) * (nraw / nnv), 1e-15f);
    float ps = proj_scale_d(pn, kv, maxn);
    scl[(size_t)lane * n + wid] = s * ps;
    xnk[(size_t)lane * n + wid] = pn * ps;
  }
}

// ---------------- bias points ----------------
__global__ void k_biaspt_all(const float* __restrict__ eb1, const float* __restrict__ eb2,
                             float* __restrict__ biasb, CurvPack cp) {
  __shared__ float l2[2];
  int blk = blockIdx.x;
  int ex = blk >> 1, layer = blk & 1;
  float kv = cp.k[ex], sk = cp.sk[ex], maxn = cp.mx[ex];
  const float* b = (layer ? eb2 : eb1) + ex * 128;
  float* outb = biasb + blk * 132;
  int j = threadIdx.x;
  float v = b[j];
  float n2 = wsum64(v * v);
  if ((j & 63) == 0) l2[j >> 6] = n2;
  __syncthreads();
  n2 = l2[0] + l2[1];
  float nraw = sqrtf(n2);
  float nnv = fmaxf(nraw, 1e-15f);
  float tk = tan_k_d(nnv, kv, sk);
  float s = tk / nnv;
  float pn = fmaxf(fabsf(tk) * (nraw / nnv), 1e-15f);
  float ps = proj_scale_d(pn, kv, maxn);
  float bp = ps * s * v;
  outb[j] = bp;
  float y2v = wsum64(bp * bp);
  __syncthreads();
  if ((j & 63) == 0) l2[j >> 6] = y2v;
  __syncthreads();
  if (j == 0) outb[128] = l2[0] + l2[1];
}

// ---------------- W -> fp16 hi/lo split ----------------
__global__ void k_w2h(const float* __restrict__ ew1, const float* __restrict__ ew2,
                      f16* __restrict__ whi, f16* __restrict__ wlo) {
  int i = blockIdx.x * 256 + threadIdx.x;
  if (i >= 8 * 16384) return;
  int slot = i >> 14;
  int r = i & 16383;
  int ex = slot >> 1, layer = slot & 1;
  float w = (layer ? ew2 : ew1)[ex * 16384 + r];
  f16 h = (f16)w;
  whi[i] = h;
  wlo[i] = (f16)(w - (float)h);
}

// ---------------- MFMA expert GEMM (fp32 A in-kernel split, f16 pair-interleaved out) --
// grid.y = expert. t4 layout (halfs): half = node*512 + (elem>>1)*8 + ex*2 + (elem&1)
__global__ __launch_bounds__(256) void k_matmfma(
    const float* __restrict__ A, int astr, int aoffPerEx, const float* __restrict__ sclB,
    const float* __restrict__ xnkB, const f16* __restrict__ whiB,
    const f16* __restrict__ wloB, const float* __restrict__ biasB, int layer,
    f16* __restrict__ tout, int n, CurvPack cp) {
  __shared__ float red[3][16][4];
  __shared__ float redT[16][4];
  __shared__ float nAs[16], nCs[16], nL[16];
  int ex = blockIdx.y;
  float kv = cp.k[ex], sk = cp.sk[ex], maxn = cp.mx[ex];
  const f16* whi = whiB + (size_t)(ex * 2 + layer) * 16384;
  const f16* wlo = wloB + (size_t)(ex * 2 + layer) * 16384;
  const float* biasb = biasB + (ex * 2 + layer) * 132;
  const float* scale = sclB + (size_t)ex * n;
  const float* xnorm = xnkB + (size_t)ex * n;

  int tid = threadIdx.x;
  int w = tid >> 6;
  int lane = tid & 63;
  int col = lane & 15;
  int quad = lane >> 4;
  int n0w = blockIdx.x * 16;
  if (n0w >= n) return;

  int anodec = min(n0w + col, n - 1);
  const float* arow = A + (size_t)anodec * astr + ex * aoffPerEx;
  int jt0 = w * 2;

  f32x4 acc[2];
  acc[0] = (f32x4){0.f, 0.f, 0.f, 0.f};
  acc[1] = (f32x4){0.f, 0.f, 0.f, 0.f};

#pragma unroll
  for (int kc = 0; kc < 4; kc++) {
    int kb = kc * 32 + quad * 8;
    float4 a0 = *(const float4*)(arow + kb);
    float4 a1 = *(const float4*)(arow + kb + 4);
    float av[8] = {a0.x, a0.y, a0.z, a0.w, a1.x, a1.y, a1.z, a1.w};
    f16x8 Ah, Al;
#pragma unroll
    for (int i = 0; i < 8; i++) {
      f16 h = (f16)av[i];
      Ah[i] = h;
      Al[i] = (f16)(av[i] - (float)h);
    }
#pragma unroll
    for (int j2 = 0; j2 < 2; j2++) {
      const f16* bh = whi + (size_t)((jt0 + j2) * 16 + col) * 128 + kb;
      const f16* bl = wlo + (size_t)((jt0 + j2) * 16 + col) * 128 + kb;
      f16x8 Bh = *(const f16x8*)bh;
      f16x8 Bl = *(const f16x8*)bl;
      acc[j2] = __builtin_amdgcn_mfma_f32_16x16x32_f16(Ah, Bh, acc[j2], 0, 0, 0);
      acc[j2] = __builtin_amdgcn_mfma_f32_16x16x32_f16(Ah, Bl, acc[j2], 0, 0, 0);
      acc[j2] = __builtin_amdgcn_mfma_f32_16x16x32_f16(Al, Bh, acc[j2], 0, 0, 0);
    }
  }

  float bpj[2];
  bpj[0] = biasb[jt0 * 16 + col];
  bpj[1] = biasb[(jt0 + 1) * 16 + col];
  float y2 = biasb[128];

#pragma unroll
  for (int r = 0; r < 4; r++) {
    float s0 = 0.f, s1 = 0.f, s2 = 0.f;
#pragma unroll
    for (int j2 = 0; j2 < 2; j2++) {
      float v = acc[j2][r];
      s0 = fmaf(v, v, s0);
      s1 += fabsf(v);
      s2 = fmaf(v, bpj[j2], s2);
    }
#pragma unroll
    for (int m = 1; m < 16; m <<= 1) {
      s0 += __shfl_xor(s0, m, 64);
      s1 += __shfl_xor(s1, m, 64);
      s2 += __shfl_xor(s2, m, 64);
    }
    if (col == 0) {
      red[0][quad * 4 + r][w] = s0;
      red[1][quad * 4 + r][w] = s1;
      red[2][quad * 4 + r][w] = s2;
    }
  }
  __syncthreads();

  if (tid < 16) {
    int gnode = min(n0w + tid, n - 1);
    float sc = scale[gnode];
    float s0f = (red[0][tid][0] + red[0][tid][1] + red[0][tid][2] + red[0][tid][3]) * sc * sc;
    float s1f = (red[1][tid][0] + red[1][tid][1] + red[1][tid][2] + red[1][tid][3]) * fabsf(sc);
    float s2f = (red[2][tid][0] + red[2][tid][1] + red[2][tid][2] + red[2][tid][3]) * sc;
    float xnr = xnorm[gnode];
    float xn = fmaxf(xnr, 1e-15f);
    float mxraw = sqrtf(s0f);
    float mxv = fmaxf(mxraw, 1e-15f);
    float ar = artan_k_d(xn, kv, sk);
    float c1 = tan_k_d(mxv / xn * ar, kv, sk);
    float s = (s1f == 0.f) ? 0.f : c1 / mxv;
    float pn = fmaxf(fabsf(c1) * (mxraw / mxv), 1e-15f);
    float ps = (s1f == 0.f) ? 1.f : proj_scale_d(pn, kv, maxn);
    s *= ps;
    float x2 = (s * s) * s0f;
    float xy = s * s2f;
    float Aa = 1.f - 2.f * kv * xy - kv * y2;
    float Cc = 1.f + kv * x2;
    float den = fmaxf(1.f - 2.f * kv * xy + (kv * kv) * x2 * y2, 1e-15f);
    nAs[tid] = Aa * s / den * sc;
    nCs[tid] = Cc / den;
  }
  __syncthreads();

#pragma unroll
  for (int r = 0; r < 4; r++) {
    int idx = quad * 4 + r;
    float Asc = nAs[idx], Cs = nCs[idx];
    float t0 = 0.f;
#pragma unroll
    for (int j2 = 0; j2 < 2; j2++) {
      float v = fmaf(Asc, acc[j2][r], Cs * bpj[j2]);
      t0 = fmaf(v, v, t0);
    }
#pragma unroll
    for (int m = 1; m < 16; m <<= 1) t0 += __shfl_xor(t0, m, 64);
    if (col == 0) redT[idx][w] = t0;
  }
  __syncthreads();

  if (tid < 16) {
    float t0f = redT[tid][0] + redT[tid][1] + redT[tid][2] + redT[tid][3];
    float nraw = sqrtf(t0f);
    float ps2 = proj_scale_d(fmaxf(nraw, 1e-15f), kv, maxn);
    float nh = fmaxf(ps2 * nraw, 1e-15f);
    nL[tid] = artan_k_d(nh, kv, sk) / nh * ps2;
  }
  __syncthreads();

#pragma unroll
  for (int r = 0; r < 4; r++) {
    int idx = quad * 4 + r;
    int gnode = n0w + idx;
    if (gnode >= n) continue;
    float Asc = nAs[idx], Cs = nCs[idx], L = nL[idx];
    f16* trow = tout + (size_t)gnode * 512;
#pragma unroll
    for (int j2 = 0; j2 < 2; j2++) {
      float v = fmaf(Asc, acc[j2][r], Cs * bpj[j2]);
      int d = (jt0 + j2) * 16 + col;
      trow[(d >> 1) * 8 + ex * 2 + (d & 1)] = (f16)(L * v);
    }
  }
}

// ---------------- fused 4-expert f16 edge sweep (packed hfma2) ----------------
// MODE 0: layer-1 -> interior runs write agg1[node][512] fp32 + scl2/xnk2.
// MODE 1: layer-2 -> per-expert logmap0(expmap0) pooling into feats.
template <int MODE>
__global__ __launch_bounds__(256) void k_aggF(
    const int2* __restrict__ esw, const int* __restrict__ off,
    const int* __restrict__ bnode, const int* __restrict__ bslot,
    const int* __restrict__ batch, const f16* __restrict__ t, float* __restrict__ agg1,
    float* __restrict__ aggc, float* __restrict__ scl2, float* __restrict__ xnk2,
    float* __restrict__ feats, int etot, int n, CurvPack cp) {
  int gw = blockIdx.x * 4 + (threadIdx.x >> 6);
  int lane = threadIdx.x & 63;
  int e0 = gw * CHUNK;
  if (e0 >= etot) return;
  int e1 = min(e0 + CHUNK, etot);
  int bnHead = bnode[gw];
  int slotA = bslot[gw];
  int slotB = ((gw + 1) * CHUNK < etot) ? bslot[gw + 1] : slotA;
  int cur = bnHead;
  int runStart = off[cur];
  int eend = off[cur + 1];
  __half2 hz = __half2half2(__float2half(0.f));
  __half2 axh[4];
#pragma unroll
  for (int e = 0; e < 4; e++) axh[e] = hz;
  float pax[4], pay[4];
#pragma unroll
  for (int e = 0; e < 4; e++) pax[e] = pay[e] = 0.f;
  int bcur = (MODE == 1) ? batch[cur] : 0;

  auto flushInterior = [&]() {
#pragma unroll
    for (int e = 0; e < 4; e++) {
      float2 f = __half22float2(axh[e]);
      if (MODE == 0) {
        ((float2*)agg1)[(size_t)cur * 256 + e * 64 + lane] = f;
        float n2 = wsum64(fmaf(f.x, f.x, f.y * f.y));
        float nraw = sqrtf(n2);
        float nnv = fmaxf(nraw, 1e-15f);
        float tk = tan_k_d(nnv, cp.k[e], cp.sk[e]);
        float s = tk / nnv;
        float pn = fmaxf(fabsf(tk) * (nraw / nnv), 1e-15f);
        float ps = proj_scale_d(pn, cp.k[e], cp.mx[e]);
        if (lane == 0) {
          scl2[(size_t)e * n + cur] = s * ps;
          xnk2[(size_t)e * n + cur] = pn * ps;
        }
      } else {
        float n2 = wsum64(fmaf(f.x, f.x, f.y * f.y));
        float nraw = sqrtf(n2);
        float nnv = fmaxf(nraw, 1e-15f);
        float tk = tan_k_d(nnv, cp.k[e], cp.sk[e]);
        float s = tk / nnv;
        float pn = fmaxf(fabsf(tk) * (nraw / nnv), 1e-15f);
        float ps = proj_scale_d(pn, cp.k[e], cp.mx[e]);
        s *= ps;
        float nh = fmaxf(pn * ps, 1e-15f);
        float sc = artan_k_d(nh, cp.k[e], cp.sk[e]) / nh * s;
        pax[e] = fmaf(sc, f.x, pax[e]);
        pay[e] = fmaf(sc, f.y, pay[e]);
      }
    }
  };
  auto flushBoundary = [&]() {
    int slot = (cur == bnHead) ? slotA : slotB;
#pragma unroll
    for (int e = 0; e < 4; e++) {
      float2 f = __half22float2(axh[e]);
      float* dp = aggc + (size_t)slot * 512 + e * 128 + lane * 2;
      atomicAdd(dp, f.x);
      atomicAdd(dp + 1, f.y);
    }
  };
  auto flushPool = [&]() {
    if (MODE == 1) {
#pragma unroll
      for (int e = 0; e < 4; e++) {
        float* fp = &feats[(size_t)bcur * 512 + e * 128 + lane * 2];
        atomicAdd(fp, pax[e]);
        atomicAdd(fp + 1, pay[e]);
      }
    }
  };

  int j = e0;
  while (j < e1) {
    if (j + 8 <= e1 && eend >= j + 8) {
      int2 m[8];
#pragma unroll
      for (int q = 0; q < 8; q++) m[q] = esw[j + q];
      uint4 rv[8];
#pragma unroll
      for (int q = 0; q < 8; q++) {
        int s = __builtin_amdgcn_readfirstlane(m[q].x);
        rv[q] = *(const uint4*)(t + (size_t)s * 512 + lane * 8);
      }
#pragma unroll
      for (int q = 0; q < 8; q++) {
        __half2 wh = __half2half2(__float2half(__int_as_float(m[q].y)));
        axh[0] = __hfma2(wh, h2cast(rv[q].x), axh[0]);
        axh[1] = __hfma2(wh, h2cast(rv[q].y), axh[1]);
        axh[2] = __hfma2(wh, h2cast(rv[q].z), axh[2]);
        axh[3] = __hfma2(wh, h2cast(rv[q].w), axh[3]);
      }
      j += 8;
    } else if (j + 4 <= e1 && eend >= j + 4) {
      int2 m[4];
#pragma unroll
      for (int q = 0; q < 4; q++) m[q] = esw[j + q];
      uint4 rv[4];
#pragma unroll
      for (int q = 0; q < 4; q++) {
        int s = __builtin_amdgcn_readfirstlane(m[q].x);
        rv[q] = *(const uint4*)(t + (size_t)s * 512 + lane * 8);
      }
#pragma unroll
      for (int q = 0; q < 4; q++) {
        __half2 wh = __half2half2(__float2half(__int_as_float(m[q].y)));
        axh[0] = __hfma2(wh, h2cast(rv[q].x), axh[0]);
        axh[1] = __hfma2(wh, h2cast(rv[q].y), axh[1]);
        axh[2] = __hfma2(wh, h2cast(rv[q].z), axh[2]);
        axh[3] = __hfma2(wh, h2cast(rv[q].w), axh[3]);
      }
      j += 4;
    } else {
      if (j == eend) {
        if (runStart >= e0) flushInterior(); else flushBoundary();
#pragma unroll
        for (int e = 0; e < 4; e++) axh[e] = hz;
        runStart = j;
        cur++;
        eend = off[cur + 1];
        if (MODE == 1) {
          int nb = batch[cur];
          if (nb != bcur) {
            flushPool();
#pragma unroll
            for (int e = 0; e < 4; e++) pax[e] = pay[e] = 0.f;
            bcur = nb;
          }
        }
      }
      int2 m = esw[j];
      int s = __builtin_amdgcn_readfirstlane(m.x);
      uint4 rv = *(const uint4*)(t + (size_t)s * 512 + lane * 8);
      __half2 wh = __half2half2(__float2half(__int_as_float(m.y)));
      axh[0] = __hfma2(wh, h2cast(rv.x), axh[0]);
      axh[1] = __hfma2(wh, h2cast(rv.y), axh[1]);
      axh[2] = __hfma2(wh, h2cast(rv.z), axh[2]);
      axh[3] = __hfma2(wh, h2cast(rv.w), axh[3]);
      j++;
    }
  }
  if (runStart >= e0 && eend <= e1) flushInterior(); else flushBoundary();
  if (MODE == 1) flushPool();
}

// ---------------- gate edge sweep (fp16 rows, 128 halfs/node) ----------------
__global__ __launch_bounds__(256) void k_aggG(
    const int2* __restrict__ esw, const int* __restrict__ off,
    const int* __restrict__ bnode, const int* __restrict__ bslot,
    const int* __restrict__ batch, const f16x2* __restrict__ t, float* __restrict__ aggc,
    const float* __restrict__ bias, float* __restrict__ hgate, int etot, int n) {
  int gw = blockIdx.x * 4 + (threadIdx.x >> 6);
  int lane = threadIdx.x & 63;
  int e0 = gw * CHUNK;
  if (e0 >= etot) return;
  int e1 = min(e0 + CHUNK, etot);
  int bnHead = bnode[gw];
  int slotA = bslot[gw];
  int slotB = ((gw + 1) * CHUNK < etot) ? bslot[gw + 1] : slotA;
  int cur = bnHead;
  int runStart = off[cur];
  int eend = off[cur + 1];
  float ax = 0.f, ay = 0.f, pax = 0.f, pay = 0.f;
  int bcur = batch[cur];
  float2 bb = ((const float2*)bias)[lane];

  auto flushInterior = [&]() {
    pax += fmaxf(ax + bb.x, 0.f);
    pay += fmaxf(ay + bb.y, 0.f);
  };
  auto flushBoundary = [&]() {
    int slot = (cur == bnHead) ? slotA : slotB;
    float* dp = aggc + (size_t)slot * 512 + lane * 2;
    atomicAdd(dp, ax);
    atomicAdd(dp + 1, ay);
  };
  auto flushPool = [&]() {
    float* hp = &hgate[(size_t)bcur * 128 + lane * 2];
    atomicAdd(hp, pax);
    atomicAdd(hp + 1, pay);
  };

  int j = e0;
  while (j < e1) {
    if (j + 8 <= e1 && eend >= j + 8) {
      int2 m[8];
#pragma unroll
      for (int q = 0; q < 8; q++) m[q] = esw[j + q];
      f16x2 r[8];
#pragma unroll
      for (int q = 0; q < 8; q++) {
        int s = __builtin_amdgcn_readfirstlane(m[q].x);
        r[q] = t[(size_t)s * 64 + lane];
      }
#pragma unroll
      for (int q = 0; q < 8; q++) {
        float w = __int_as_float(m[q].y);
        ax = fmaf(w, (float)r[q][0], ax);
        ay = fmaf(w, (float)r[q][1], ay);
      }
      j += 8;
    } else if (j + 4 <= e1 && eend >= j + 4) {
      int2 m[4];
#pragma unroll
      for (int q = 0; q < 4; q++) m[q] = esw[j + q];
      f16x2 r[4];
#pragma unroll
      for (int q = 0; q < 4; q++) {
        int s = __builtin_amdgcn_readfirstlane(m[q].x);
        r[q] = t[(size_t)s * 64 + lane];
      }
#pragma unroll
      for (int q = 0; q < 4; q++) {
        float w = __int_as_float(m[q].y);
        ax = fmaf(w, (float)r[q][0], ax);
        ay = fmaf(w, (float)r[q][1], ay);
      }
      j += 4;
    } else {
      if (j == eend) {
        if (runStart >= e0) flushInterior(); else flushBoundary();
        ax = ay = 0.f;
        runStart = j;
        cur++;
        eend = off[cur + 1];
        int nb = batch[cur];
        if (nb != bcur) {
          flushPool();
          pax = pay = 0.f;
          bcur = nb;
        }
      }
      int2 m = esw[j];
      int s = __builtin_amdgcn_readfirstlane(m.x);
      f16x2 rv = t[(size_t)s * 64 + lane];
      float w = __int_as_float(m.y);
      ax = fmaf(w, (float)rv[0], ax);
      ay = fmaf(w, (float)rv[1], ay);
      j++;
    }
  }
  if (runStart >= e0 && eend <= e1) flushInterior(); else flushBoundary();
  flushPool();
}

// ---------------- fixups for chunk-spanning runs ----------------
__global__ void k_fix1(const int* __restrict__ bnode, const int* __restrict__ bslot,
                       const int* __restrict__ off, const float* __restrict__ aggc,
                       float* __restrict__ agg1, float* __restrict__ scl2,
                       float* __restrict__ xnk2, int nchunk, int n, CurvPack cp) {
  int g = blockIdx.x * 4 + (threadIdx.x >> 6);
  int lane = threadIdx.x & 63;
  if (g >= nchunk) return;
  int nd;
  if (!span_head(bnode, bslot, off, g, nd)) return;
#pragma unroll
  for (int e = 0; e < 4; e++) {
    float2 v = ((const float2*)aggc)[(size_t)g * 256 + e * 64 + lane];
    ((float2*)agg1)[(size_t)nd * 256 + e * 64 + lane] = v;
    float n2 = wsum64(fmaf(v.x, v.x, v.y * v.y));
    float nraw = sqrtf(n2);
    float nnv = fmaxf(nraw, 1e-15f);
    float tk = tan_k_d(nnv, cp.k[e], cp.sk[e]);
    float s = tk / nnv;
    float pn = fmaxf(fabsf(tk) * (nraw / nnv), 1e-15f);
    float ps = proj_scale_d(pn, cp.k[e], cp.mx[e]);
    if (lane == 0) {
      scl2[(size_t)e * n + nd] = s * ps;
      xnk2[(size_t)e * n + nd] = pn * ps;
    }
  }
}

__global__ void k_fix2(const int* __restrict__ bnode, const int* __restrict__ bslot,
                       const int* __restrict__ off, const float* __restrict__ aggc,
                       const int* __restrict__ batch, float* __restrict__ feats, int nchunk,
                       CurvPack cp) {
  int g = blockIdx.x * 4 + (threadIdx.x >> 6);
  int lane = threadIdx.x & 63;
  if (g >= nchunk) return;
  int nd;
  if (!span_head(bnode, bslot, off, g, nd)) return;
  int b = batch[nd];
#pragma unroll
  for (int e = 0; e < 4; e++) {
    float2 v = ((const float2*)aggc)[(size_t)g * 256 + e * 64 + lane];
    float n2 = wsum64(fmaf(v.x, v.x, v.y * v.y));
    float nraw = sqrtf(n2);
    float nnv = fmaxf(nraw, 1e-15f);
    float tk = tan_k_d(nnv, cp.k[e], cp.sk[e]);
    float s = tk / nnv;
    float pn = fmaxf(fabsf(tk) * (nraw / nnv), 1e-15f);
    float ps = proj_scale_d(pn, cp.k[e], cp.mx[e]);
    s *= ps;
    float nh = fmaxf(pn * ps, 1e-15f);
    float sc = artan_k_d(nh, cp.k[e], cp.sk[e]) / nh * s;
    float* fp = &feats[(size_t)b * 512 + e * 128 + lane * 2];
    atomicAdd(fp, sc * v.x);
    atomicAdd(fp + 1, sc * v.y);
  }
}

__global__ void k_fixG(const int* __restrict__ bnode, const int* __restrict__ bslot,
                       const int* __restrict__ off, const float* __restrict__ aggc,
                       const int* __restrict__ batch, const float* __restrict__ bias,
                       float* __restrict__ hgate, int nchunk) {
  int g = blockIdx.x * 4 + (threadIdx.x >> 6);
  int lane = threadIdx.x & 63;
  if (g >= nchunk) return;
  int nd;
  if (!span_head(bnode, bslot, off, g, nd)) return;
  float2 v = ((const float2*)aggc)[(size_t)g * 256 + lane];
  float2 bb = ((const float2*)bias)[lane];
  int b = batch[nd];
  float* hp = &hgate[(size_t)b * 128 + lane * 2];
  atomicAdd(hp, fmaxf(v.x + bb.x, 0.f));
  atomicAdd(hp + 1, fmaxf(v.y + bb.y, 0.f));
}

// ---------------- gate GEMM 1 ----------------
__global__ __launch_bounds__(256) void k_gate1(const float* __restrict__ x,
                                               const float* __restrict__ gw1,
                                               float* __restrict__ m1, int n) {
  __shared__ float xT[64][68];
  __shared__ float Wt[64][36];
  int tid = threadIdx.x;
  int n0 = blockIdx.x * 64;
  int c = tid & 7, r = tid >> 3;
  float acc[2][4];
#pragma unroll
  for (int i = 0; i < 2; i++)
#pragma unroll
    for (int jj = 0; jj < 4; jj++) acc[i][jj] = 0.f;

  for (int kc = 0; kc < 2; kc++) {
    if (kc) __syncthreads();
#pragma unroll
    for (int it = 0; it < 8; it++) {
      int u = tid + it * 256;
      int j = u >> 6, kd = u & 63;
      Wt[kd][j] = gw1[j * 128 + kc * 64 + kd];
    }
#pragma unroll
    for (int it = 0; it < 4; it++) {
      int u = tid + it * 256;
      int node = u >> 4, c4 = u & 15;
      float4 v = make_float4(0.f, 0.f, 0.f, 0.f);
      if (n0 + node < n) v = ((const float4*)x)[(size_t)(n0 + node) * 32 + kc * 16 + c4];
      xT[4 * c4 + 0][node] = v.x;
      xT[4 * c4 + 1][node] = v.y;
      xT[4 * c4 + 2][node] = v.z;
      xT[4 * c4 + 3][node] = v.w;
    }
    __syncthreads();
#pragma unroll 8
    for (int kd = 0; kd < 64; kd++) {
      float2 av = *(const float2*)&xT[kd][r * 2];
      float4 bv = *(const float4*)&Wt[kd][c * 4];
      float a[2] = {av.x, av.y};
      float bbv[4] = {bv.x, bv.y, bv.z, bv.w};
#pragma unroll
      for (int i = 0; i < 2; i++)
#pragma unroll
        for (int jj = 0; jj < 4; jj++) acc[i][jj] = fmaf(a[i], bbv[jj], acc[i][jj]);
    }
  }
#pragma unroll
  for (int i = 0; i < 2; i++) {
    int node = n0 + r * 2 + i;
    if (node >= n) continue;
    ((float4*)m1)[(size_t)node * 8 + c] = make_float4(acc[i][0], acc[i][1], acc[i][2], acc[i][3]);
  }
}

// ---------------- gate GEMM 2 (fp16 out, row 128 halfs) ----------------
__global__ __launch_bounds__(256) void k_gate2(const float* __restrict__ g1,
                                               const float* __restrict__ gw2,
                                               f16* __restrict__ m2, int n) {
  __shared__ float xT[32][68];
  __shared__ float Wt[32][132];
  int tid = threadIdx.x;
  int n0 = blockIdx.x * 64;
  int c = tid & 15, r = tid >> 4;
  float acc[4][8];
#pragma unroll
  for (int i = 0; i < 4; i++)
#pragma unroll
    for (int jj = 0; jj < 8; jj++) acc[i][jj] = 0.f;

#pragma unroll
  for (int it = 0; it < 16; it++) {
    int u = tid + it * 256;
    int j = u >> 5, kd = u & 31;
    Wt[kd][j] = gw2[j * 32 + kd];
  }
#pragma unroll
  for (int it = 0; it < 2; it++) {
    int u = tid + it * 256;
    int node = u >> 3, c4 = u & 7;
    float4 v = make_float4(0.f, 0.f, 0.f, 0.f);
    if (n0 + node < n) v = ((const float4*)g1)[(size_t)(n0 + node) * 8 + c4];
    xT[4 * c4 + 0][node] = v.x;
    xT[4 * c4 + 1][node] = v.y;
    xT[4 * c4 + 2][node] = v.z;
    xT[4 * c4 + 3][node] = v.w;
  }
  __syncthreads();
#pragma unroll 8
  for (int kd = 0; kd < 32; kd++) {
    float4 av = *(const float4*)&xT[kd][r * 4];
    float4 b0 = *(const float4*)&Wt[kd][c * 8];
    float4 b1 = *(const float4*)&Wt[kd][c * 8 + 4];
    float a[4] = {av.x, av.y, av.z, av.w};
    float bbv[8] = {b0.x, b0.y, b0.z, b0.w, b1.x, b1.y, b1.z, b1.w};
#pragma unroll
    for (int i = 0; i < 4; i++)
#pragma unroll
      for (int jj = 0; jj < 8; jj++) acc[i][jj] = fmaf(a[i], bbv[jj], acc[i][jj]);
  }
#pragma unroll
  for (int i = 0; i < 4; i++) {
    int node = n0 + r * 4 + i;
    if (node >= n) continue;
    f16x8 hv;
#pragma unroll
    for (int jj = 0; jj < 8; jj++) hv[jj] = (f16)acc[i][jj];
    *((f16x8*)(m2 + (size_t)node * 128) + c) = hv;
  }
}

// ---------------- gate aggregation dim32 ----------------
__global__ void k_agg_relu32(const float* __restrict__ m1, const int* __restrict__ off,
                             const int2* __restrict__ esw, const float* __restrict__ bias,
                             float* __restrict__ g1, int n) {
  int node = blockIdx.x * 4 + (threadIdx.x >> 6);
  int lane = threadIdx.x & 63;
  if (node >= n) return;
  int grp = lane >> 3, l8 = lane & 7;
  int e0 = off[node], e1 = off[node + 1];
  float4 acc = make_float4(0.f, 0.f, 0.f, 0.f);
  for (int base = e0 + grp; base < e1; base += 8) {
    int2 me = esw[base];
    int ss = me.x;
    float ww = __int_as_float(me.y);
    float4 tv = ((const float4*)m1)[(size_t)ss * 8 + l8];
    acc.x = fmaf(ww, tv.x, acc.x);
    acc.y = fmaf(ww, tv.y, acc.y);
    acc.z = fmaf(ww, tv.z, acc.z);
    acc.w = fmaf(ww, tv.w, acc.w);
  }
#pragma unroll
  for (int m = 8; m <= 32; m <<= 1) {
    acc.x += __shfl_xor(acc.x, m, 64);
    acc.y += __shfl_xor(acc.y, m, 64);
    acc.z += __shfl_xor(acc.z, m, 64);
    acc.w += __shfl_xor(acc.w, m, 64);
  }
  if (grp == 0) {
    float4 bb = ((const float4*)bias)[l8];
    float4 o = make_float4(fmaxf(acc.x + bb.x, 0.f), fmaxf(acc.y + bb.y, 0.f),
                           fmaxf(acc.z + bb.z, 0.f), fmaxf(acc.w + bb.w, 0.f));
    ((float4*)g1)[(size_t)node * 8 + l8] = o;
  }
}

// ---------------- final ----------------
__global__ __launch_bounds__(128) void k_final(const float* __restrict__ feats,
                                               const float* __restrict__ hgate,
                                               const float* __restrict__ counts,
                                               const float* __restrict__ gate_u,
                                               const float* __restrict__ tau_raw,
                                               float* __restrict__ out, CurvPack cp) {
  __shared__ float l2[2];
  int b = blockIdx.x;
  int j = threadIdx.x;
  float cnt = fmaxf(counts[b], 1.f);
  float hg = hgate[(size_t)b * 128 + j] / cnt;

  auto bsum = [&](float v) -> float {
    v = wsum64(v);
    __syncthreads();
    if ((j & 63) == 0) l2[j >> 6] = v;
    __syncthreads();
    return l2[0] + l2[1];
  };

  float nhg2 = bsum(hg * hg);
  float nhgraw = sqrtf(nhg2);
  float nhg = fmaxf(nhgraw, 1e-15f);

  float d[4], tau[4];
#pragma unroll
  for (int i = 0; i < 4; i++) {
    float kv = cp.k[i], sk = cp.sk[i], mxn = cp.mx[i];
    float tk = tan_k_d(nhg, kv, sk);
    float s = tk / nhg;
    float pn = fmaxf(fabsf(tk) * (nhgraw / nhg), 1e-15f);
    s *= proj_scale_d(pn, kv, mxn);
    float zk = s * hg;

    float u = gate_u[i * 128 + j];
    float nu2 = bsum(u * u);
    float nuraw = sqrtf(nu2);
    float nu = fmaxf(nuraw, 1e-15f);
    float tku = tan_k_d(nu, kv, sk);
    float su = tku / nu;
    float pnu = fmaxf(fabsf(tku) * (nuraw / nu), 1e-15f);
    su *= proj_scale_d(pnu, kv, mxn);
    float yk = su * u;

    float xv = -zk;
    float x2 = bsum(xv * xv);
    float y2 = bsum(yk * yk);
    float xy = bsum(xv * yk);
    float A = 1.f - 2.f * kv * xy - kv * y2;
    float C = 1.f + kv * x2;
    float den = fmaxf(1.f - 2.f * kv * xy + (kv * kv) * x2 * y2, 1e-15f);
    float ma = (A * xv + C * yk) / den;
    float m2 = bsum(ma * ma);
    float mraw = sqrtf(m2);
    float ps2 = proj_scale_d(fmaxf(mraw, 1e-15f), kv, mxn);
    float nm = fmaxf(ps2 * mraw, 1e-15f);
    d[i] = 2.f * artan_k_d(nm, kv, sk);

    float tr = tau_raw[i];
    tau[i] = fminf(fmaxf(log1pf(expf(tr)) + 0.05f, 0.05f), 10.f);
  }

  float xi[4];
  float mxv = -1e30f;
#pragma unroll
  for (int i = 0; i < 4; i++) {
    xi[i] = -d[i] / tau[i];
    mxv = fmaxf(mxv, xi[i]);
  }
  float es = 0.f, e[4];
#pragma unroll
  for (int i = 0; i < 4; i++) {
    e[i] = expf(xi[i] - mxv);
    es += e[i];
  }
  float w[4];
#pragma unroll
  for (int i = 0; i < 4; i++) w[i] = e[i] / es;

#pragma unroll
  for (int i = 0; i < 4; i++)
    out[(size_t)b * 512 + i * 128 + j] = feats[(size_t)b * 512 + i * 128 + j] / cnt * w[i];

  if (j < 4) {
    out[65536 + b * 4 + j] = w[j];
    out[66048 + b * 4 + j] = d[j];
  }
  if (b == 0 && j < 4) out[66560 + j] = tau[j];
}

// ---------------- host launcher ----------------
extern "C" void kernel_launch(void* const* d_in, const int* in_sizes, int n_in,
                              void* d_out, int out_size, void* d_ws, size_t ws_size,
                              hipStream_t stream) {
  const float* x = (const float*)d_in[0];
  const int* ei = (const int*)d_in[1];
  const int* batch = (const int*)d_in[2];
  const float* ew1 = (const float*)d_in[3];
  const float* eb1 = (const float*)d_in[4];
  const float* ew2 = (const float*)d_in[5];
  const float* eb2 = (const float*)d_in[6];
  const float* gw1 = (const float*)d_in[7];
  const float* gb1 = (const float*)d_in[8];
  const float* gw2 = (const float*)d_in[9];
  const float* gb2 = (const float*)d_in[10];
  const float* gu = (const float*)d_in[11];
  const float* traw = (const float*)d_in[12];
  float* out = (float*)d_out;

  const int N = NN, E = EE, ET = ETOT, B = BB;

  float* ws = (float*)d_ws;
  size_t o = 0;
  f16* t4 = (f16*)ws;       o += (size_t)N * 256;  // N*512 halfs pair-interleaved
  float* agg1 = ws + o;     o += (size_t)N * 512;
  float* aggc = ws + o;     o += (size_t)NCHUNK * 512;
  float* deg = ws + o;      o += N;
  float* scl1 = ws + o;     o += (size_t)4 * N;
  float* xnk1 = ws + o;     o += (size_t)4 * N;
  float* scl2 = ws + o;     o += (size_t)4 * N;
  float* xnk2 = ws + o;     o += (size_t)4 * N;
  float* counts = ws + o;   o += 256;
  float* feats = ws + o;    o += (size_t)B * 512;
  float* hg = ws + o;       o += (size_t)B * 128;
  float* biasb = ws + o;    o += 8 * 132;
  f16* whi = (f16*)(ws + o);    o += 8 * 16384 / 2;
  f16* wlo = (f16*)(ws + o);    o += 8 * 16384 / 2;
  int* ideg = (int*)(ws + o);   o += N;
  int* csroff = (int*)(ws + o); o += N + 8;
  int* cursor = (int*)(ws + o); o += N;
  int* boff = (int*)(ws + o);   o += 136;
  int* bsum = (int*)(ws + o);   o += 256;
  int* bnode = (int*)(ws + o);  o += NCHUNK + 8;
  int* bslot = (int*)(ws + o);  o += NCHUNK + 8;
  int2* esw = (int2*)(ws + o);  o += (size_t)2 * ET;

  float* m1 = agg1;                       // gate scratch aliases agg1
  float* g1 = agg1 + (size_t)N * 32;
  f16* tg = t4;                           // gate fp16 rows alias t4

  hipMemsetAsync(counts, 0, (256 + (size_t)B * 512 + (size_t)B * 128) * sizeof(float), stream);

  const double curvs[4] = {-1.0, 0.0, 1.0, -0.5};
  CurvPack cp;
  for (int i = 0; i < 4; i++) {
    double kd = curvs[i];
    double skd = sqrt(fabs(kd));
    cp.k[i] = (float)kd;
    cp.sk[i] = (float)skd;
    cp.mx[i] = (kd < 0) ? (float)((1.0 - 1e-5) / skd) : 3.0e38f;
  }

  k_init<<<(N + 255) / 256, 256, 0, stream>>>(deg, N);
  k_counts<<<1, 256, 0, stream>>>(batch, boff, counts, N);
  k_deg<<<(E + 255) / 256, 256, 0, stream>>>(ei, deg, E);
  k_dinv<<<(N + 255) / 256, 256, 0, stream>>>(deg, ideg, N);
  k_scanA<<<SCB, 256, 0, stream>>>(ideg, bsum, N);
  k_scanB<<<1, 256, 0, stream>>>(bsum, SCB);
  k_scanC<<<SCB, 256, 0, stream>>>(ideg, bsum, csroff, cursor, N);
  k_bnodes<<<(NCHUNK + 255) / 256, 256, 0, stream>>>(csroff, bnode, NCHUNK, N);
  k_bslot<<<(NCHUNK + 255) / 256, 256, 0, stream>>>(bnode, bslot, NCHUNK);
  k_place<<<(ET + 255) / 256, 256, 0, stream>>>(ei, deg, cursor, esw, E, N);
  k_nodeprep<<<(N + 3) / 4, 256, 0, stream>>>(x, scl1, xnk1, N, cp);
  k_biaspt_all<<<8, 128, 0, stream>>>(eb1, eb2, biasb, cp);
  k_w2h<<<512, 256, 0, stream>>>(ew1, ew2, whi, wlo);

  const int aggBlocks = (NCHUNK + 3) / 4;
  dim3 mfmaGrid((N + 15) / 16, 4);

  // ---- layer 1 (all 4 experts fused, f16 pair-interleaved t) ----
  k_matmfma<<<mfmaGrid, 256, 0, stream>>>(x, 128, 0, scl1, xnk1, whi, wlo, biasb, 0, t4, N, cp);
  k_zeroc<<<aggBlocks, 256, 0, stream>>>(bnode, bslot, csroff, aggc, NCHUNK);
  k_aggF<0><<<aggBlocks, 256, 0, stream>>>(esw, csroff, bnode, bslot, batch, t4, agg1, aggc,
                                           scl2, xnk2, nullptr, ET, N, cp);
  k_fix1<<<aggBlocks, 256, 0, stream>>>(bnode, bslot, csroff, aggc, agg1, scl2, xnk2, NCHUNK, N,
                                        cp);
  // ---- layer 2 ----
  k_matmfma<<<mfmaGrid, 256, 0, stream>>>(agg1, 512, 128, scl2, xnk2, whi, wlo, biasb, 1, t4, N,
                                          cp);
  k_zeroc<<<aggBlocks, 256, 0, stream>>>(bnode, bslot, csroff, aggc, NCHUNK);
  k_aggF<1><<<aggBlocks, 256, 0, stream>>>(esw, csroff, bnode, bslot, batch, t4, nullptr, aggc,
                                           nullptr, nullptr, feats, ET, N, cp);
  k_fix2<<<aggBlocks, 256, 0, stream>>>(bnode, bslot, csroff, aggc, batch, feats, NCHUNK, cp);

  // ---- gate GCN ----
  k_gate1<<<(N + 63) / 64, 256, 0, stream>>>(x, gw1, m1, N);
  k_agg_relu32<<<(N + 3) / 4, 256, 0, stream>>>(m1, csroff, esw, gb1, g1, N);
  k_gate2<<<(N + 63) / 64, 256, 0, stream>>>(g1, gw2, tg, N);
  k_zeroc<<<aggBlocks, 256, 0, stream>>>(bnode, bslot, csroff, aggc, NCHUNK);
  k_aggG<<<aggBlocks, 256, 0, stream>>>(esw, csroff, bnode, bslot, batch, (const f16x2*)tg,
                                        aggc, gb2, hg, ET, N);
  k_fixG<<<aggBlocks, 256, 0, stream>>>(bnode, bslot, csroff, aggc, batch, gb2, hg, NCHUNK);

  k_final<<<B, 128, 0, stream>>>(feats, hg, counts, gu, traw, out, cp);

  (void)in_sizes; (void)n_in; (void)out_size; (void)ws_size;
}